// Round 7
// baseline (401.311 us; speedup 1.0000x reference)
//
#include <hip/hip_runtime.h>

// LQR KKT via backward Riccati + forward rollout; mu_t = P_t x_t (stable).
// Round-7 = BISECTION: exact round-3 kernel (passed, 390us) with ONLY the
// G phase replaced by the 4x4-tiled outer-product form (the construct shared
// by all failing rounds 4-6). Everything else is byte-identical to r3.
//
// Dims: n_state=32, n_input=16, n_all=48, T=64.

namespace {

constexpr int NS  = 32;
constexpr int NI  = 16;
constexpr int NA  = 48;
constexpr int TT  = 64;
constexpr int NTH = 256;

__device__ __forceinline__ void fma4(float4& a, float s, const float4& b) {
  a.x += s * b.x; a.y += s * b.y; a.z += s * b.z; a.w += s * b.w;
}
__device__ __forceinline__ void fms4(float4& a, float s, const float4& b) {
  a.x -= s * b.x; a.y -= s * b.y; a.z -= s * b.z; a.w -= s * b.w;
}

__global__ __launch_bounds__(NTH, 1) void lqr_riccati(
    const float* __restrict__ A,
    const float* __restrict__ Bm,
    const float* __restrict__ C,     // [TT][NA][NA]
    const float* __restrict__ x0,
    float* __restrict__ out,         // [TT*NA] tau then [TT*NS] mu
    float* __restrict__ Kall,        // scratch: TT*NI*NS floats
    float* __restrict__ Pall)        // scratch: TT*NS*NS floats
{
  __shared__ float sAB[NS][NA];   // [A | B]
  __shared__ float sP [NS][NS];   // P_{t+1}
  __shared__ float sG [NS][NA];   // P-ish @ [A B]  (this round: P^T AB)
  __shared__ float sF [NA][NA];   // C_t + [A B]^T G
  __shared__ float sK [NI][NS];   // K_t
  __shared__ float sZ [TT][NA];   // trajectory z_t = (x_t, u_t)

  const int tid  = threadIdx.x;
  const int lane = tid & 63;
  const int wid  = tid >> 6;

  // stage [A | B], zero P
  for (int e = tid; e < NS * NA; e += NTH) {
    int i = e / NA, j = e - i * NA;
    sAB[i][j] = (j < NS) ? A[i * NS + j] : Bm[i * NI + (j - NS)];
  }
  for (int e = tid; e < NS * NS; e += NTH) sP[e >> 5][e & 31] = 0.0f;
  __syncthreads();

  // ---------------- backward Riccati ----------------
  for (int t = TT - 1; t >= 0; --t) {
    // prefetch C_t (576 float4 blocks; coalesced). Consumed by F below ->
    // latency hides under the G GEMM.   [identical to r3]
    const float4* Ct4 = (const float4*)(C + (size_t)t * NA * NA);
    float4 c0 = Ct4[tid];
    float4 c1 = Ct4[tid + 256];
    float4 c2 = (tid < 64) ? Ct4[tid + 512] : make_float4(0.f, 0.f, 0.f, 0.f);

    // G phase — THE ONLY CHANGE vs r3: 4x4-tiled outer product on threads
    // 0..95. G[i][k] = sum_m P[m][i] * AB[m][k]  (= (P^T AB)[i][k]; P is
    // symmetric to ulps, and F = AB^T G stays symmetric-to-ulps either way).
    if (tid < 96) {
      const int gi = tid / 12, gk = tid - 12 * gi;   // 8 x 12 tiles of 4x4
      float4 a0 = make_float4(0.f, 0.f, 0.f, 0.f);
      float4 a1 = make_float4(0.f, 0.f, 0.f, 0.f);
      float4 a2 = make_float4(0.f, 0.f, 0.f, 0.f);
      float4 a3 = make_float4(0.f, 0.f, 0.f, 0.f);
      #pragma unroll
      for (int m = 0; m < NS; ++m) {
        const float4 vp = *(const float4*)&sP[m][4 * gi];
        const float4 vb = *(const float4*)&sAB[m][4 * gk];
        fma4(a0, vp.x, vb); fma4(a1, vp.y, vb);
        fma4(a2, vp.z, vb); fma4(a3, vp.w, vb);
      }
      *(float4*)&sG[4 * gi + 0][4 * gk] = a0;
      *(float4*)&sG[4 * gi + 1][4 * gk] = a1;
      *(float4*)&sG[4 * gi + 2][4 * gk] = a2;
      *(float4*)&sG[4 * gi + 3][4 * gk] = a3;
    }
    __syncthreads();

    // F = C_t + [A B]^T G  (48x48 = 576 float4-blocks)   [identical to r3]
    {
      int j = tid / 12, kq = tid % 12;
      float4 acc = c0;
      #pragma unroll
      for (int i = 0; i < NS; ++i)
        fma4(acc, sAB[i][j], *(const float4*)&sG[i][4 * kq]);
      *(float4*)&sF[j][4 * kq] = acc;

      int b1 = tid + 256, j1 = b1 / 12, k1 = b1 % 12;
      float4 a1 = c1;
      #pragma unroll
      for (int i = 0; i < NS; ++i)
        fma4(a1, sAB[i][j1], *(const float4*)&sG[i][4 * k1]);
      *(float4*)&sF[j1][4 * k1] = a1;

      if (tid < 64) {
        int b2 = tid + 512, j2 = b2 / 12, k2 = b2 % 12;
        float4 a2 = c2;
        #pragma unroll
        for (int i = 0; i < NS; ++i)
          fma4(a2, sAB[i][j2], *(const float4*)&sG[i][4 * k2]);
        *(float4*)&sF[j2][4 * k2] = a2;
      }
    }
    __syncthreads();

    // Gauss-Jordan on M = [Fuu | Fux] (16x48), entirely in wave 0 registers.
    // [identical to r3]
    if (wid == 0) {
      const int col = (lane < 16) ? (NS + lane) : (lane - 16);
      float f[NI];
      #pragma unroll
      for (int i = 0; i < NI; ++i) f[i] = sF[NS + i][col];
      #pragma unroll
      for (int k = 0; k < NI; ++k) {
        float m[NI];
        #pragma unroll
        for (int i = 0; i < NI; ++i) m[i] = __shfl(f[i], k);
        const float inv = 1.0f / m[k];
        f[k] *= inv;
        #pragma unroll
        for (int i = 0; i < NI; ++i)
          if (i != k) f[i] -= m[i] * f[k];
      }
      // cols 16..47 now hold K (16x32)
      if (lane >= 16 && lane < 48) {
        const int b = lane - 16;
        #pragma unroll
        for (int i = 0; i < NI; ++i) {
          sK[i][b] = f[i];
          Kall[(size_t)t * NI * NS + i * NS + b] = f[i];
        }
      }
    }
    __syncthreads();

    // P = Fxx - Fxu @ K  (32x32 = 256 float4-blocks, one per thread)
    // [identical to r3]
    {
      int a = tid >> 3, bq = tid & 7;
      float4 acc = *(const float4*)&sF[a][4 * bq];
      #pragma unroll
      for (int i = 0; i < NI; ++i)
        fms4(acc, sF[a][NS + i], *(const float4*)&sK[i][4 * bq]);
      *(float4*)&sP[a][4 * bq] = acc;
      *((float4*)Pall + (size_t)t * 256 + tid) = acc;
    }
    __syncthreads();
  }

  // ---------------- forward rollout ----------------   [identical to r3]
  if (tid < NS) sZ[0][tid] = x0[tid];
  __syncthreads();
  for (int t = 0; t < TT; ++t) {
    if (tid < NI) {
      const float4* Kr = (const float4*)(Kall + (size_t)t * NI * NS + tid * NS);
      float acc = 0.0f;
      #pragma unroll
      for (int q = 0; q < 8; ++q) {
        float4 k4 = Kr[q];
        acc += k4.x * sZ[t][4 * q]     + k4.y * sZ[t][4 * q + 1]
             + k4.z * sZ[t][4 * q + 2] + k4.w * sZ[t][4 * q + 3];
      }
      sZ[t][NS + tid] = -acc;        // u_t = -K_t x_t
    }
    __syncthreads();
    if (t < TT - 1 && tid < NS) {
      float acc = 0.0f;
      #pragma unroll
      for (int q = 0; q < 12; ++q) {
        float4 a4 = *(const float4*)&sAB[tid][4 * q];
        acc += a4.x * sZ[t][4 * q]     + a4.y * sZ[t][4 * q + 1]
             + a4.z * sZ[t][4 * q + 2] + a4.w * sZ[t][4 * q + 3];
      }
      sZ[t + 1][tid] = acc;          // x_{t+1}
    }
    __syncthreads();
  }

  // write tau
  for (int e = tid; e < TT * NA; e += NTH) {
    int t = e / NA;
    out[e] = sZ[t][e - t * NA];
  }

  // mu_t = (t==0 ? -1 : +1) * P_t x_t  (parallel over all t)
  for (int e = tid; e < TT * NS; e += NTH) {
    int t = e >> 5, i = e & 31;
    const float4* Pr = (const float4*)(Pall + (size_t)t * NS * NS + i * NS);
    float acc = 0.0f;
    #pragma unroll
    for (int q = 0; q < 8; ++q) {
      float4 p4 = Pr[q];
      acc += p4.x * sZ[t][4 * q]     + p4.y * sZ[t][4 * q + 1]
           + p4.z * sZ[t][4 * q + 2] + p4.w * sZ[t][4 * q + 3];
    }
    out[NA * TT + e] = (t == 0) ? -acc : acc;
  }
}

} // namespace

extern "C" void kernel_launch(void* const* d_in, const int* in_sizes, int n_in,
                              void* d_out, int out_size, void* d_ws, size_t ws_size,
                              hipStream_t stream) {
  const float* A  = (const float*)d_in[0];
  const float* B  = (const float*)d_in[1];
  const float* C  = (const float*)d_in[2];
  // d_in[3] is T (==64, compile-time constant here)
  const float* x0 = (const float*)d_in[4];
  float* out  = (float*)d_out;
  float* Kall = (float*)d_ws;                        // 128 KB
  float* Pall = (float*)d_ws + (size_t)TT * NI * NS; // 256 KB

  hipLaunchKernelGGL(lqr_riccati, dim3(1), dim3(NTH), 0, stream,
                     A, B, C, x0, out, Kall, Pall);
}

// Round 8
// 379.390 us; speedup vs baseline: 1.0578x; 1.0578x over previous
//
#include <hip/hip_runtime.h>

// LQR KKT via backward Riccati + forward rollout; mu_t = P_t x_t (stable).
// Round-8 = r7 (passing) + outer-product F phase on the FULL sF[48][48]
// (144 4x4 tiles, per-tile C register prefetch at step top). GJ and P-update
// remain byte-identical to r7/r3. This avoids the r4-6 sFu/sFxx split and
// transposed P-update (the remaining curse suspects).
//
// Dims: n_state=32, n_input=16, n_all=48, T=64.

namespace {

constexpr int NS  = 32;
constexpr int NI  = 16;
constexpr int NA  = 48;
constexpr int TT  = 64;
constexpr int NTH = 256;

__device__ __forceinline__ void fma4(float4& a, float s, const float4& b) {
  a.x += s * b.x; a.y += s * b.y; a.z += s * b.z; a.w += s * b.w;
}
__device__ __forceinline__ void fms4(float4& a, float s, const float4& b) {
  a.x -= s * b.x; a.y -= s * b.y; a.z -= s * b.z; a.w -= s * b.w;
}
__device__ __forceinline__ void add4(float4& a, const float4& b) {
  a.x += b.x; a.y += b.y; a.z += b.z; a.w += b.w;
}

__global__ __launch_bounds__(NTH, 1) void lqr_riccati(
    const float* __restrict__ A,
    const float* __restrict__ Bm,
    const float* __restrict__ C,     // [TT][NA][NA]
    const float* __restrict__ x0,
    float* __restrict__ out,         // [TT*NA] tau then [TT*NS] mu
    float* __restrict__ Kall,        // scratch: TT*NI*NS floats
    float* __restrict__ Pall)        // scratch: TT*NS*NS floats
{
  __shared__ float sAB[NS][NA];   // [A | B]
  __shared__ float sP [NS][NS];   // P_{t+1}
  __shared__ float sG [NS][NA];   // P^T @ [A B]
  __shared__ float sF [NA][NA];   // C_t + [A B]^T G
  __shared__ float sK [NI][NS];   // K_t
  __shared__ float sZ [TT][NA];   // trajectory z_t = (x_t, u_t)

  const int tid  = threadIdx.x;
  const int lane = tid & 63;
  const int wid  = tid >> 6;

  // stage [A | B], zero P
  for (int e = tid; e < NS * NA; e += NTH) {
    int i = e / NA, j = e - i * NA;
    sAB[i][j] = (j < NS) ? A[i * NS + j] : Bm[i * NI + (j - NS)];
  }
  for (int e = tid; e < NS * NS; e += NTH) sP[e >> 5][e & 31] = 0.0f;
  __syncthreads();

  // ---------------- backward Riccati ----------------
  for (int t = TT - 1; t >= 0; --t) {
    const float* Ct = C + (size_t)t * NA * NA;

    // Per-tile C prefetch for the F phase (tid<144 owns F tile [4fi..][4fk..]).
    // Issued at step top -> global latency hides under the G GEMM.
    const int fi = tid / 12, fk = tid - 12 * fi;   // valid tile coords for tid<144
    float4 cr0 = make_float4(0.f, 0.f, 0.f, 0.f);
    float4 cr1 = make_float4(0.f, 0.f, 0.f, 0.f);
    float4 cr2 = make_float4(0.f, 0.f, 0.f, 0.f);
    float4 cr3 = make_float4(0.f, 0.f, 0.f, 0.f);
    if (tid < 144) {
      cr0 = *(const float4*)&Ct[(4 * fi + 0) * NA + 4 * fk];
      cr1 = *(const float4*)&Ct[(4 * fi + 1) * NA + 4 * fk];
      cr2 = *(const float4*)&Ct[(4 * fi + 2) * NA + 4 * fk];
      cr3 = *(const float4*)&Ct[(4 * fi + 3) * NA + 4 * fk];
    }

    // G[i][k] = sum_m P[m][i] * AB[m][k]   (96 4x4 tiles, threads 0..95)
    // [identical to r7]
    if (tid < 96) {
      const int gi = tid / 12, gk = tid - 12 * gi;
      float4 a0 = make_float4(0.f, 0.f, 0.f, 0.f);
      float4 a1 = make_float4(0.f, 0.f, 0.f, 0.f);
      float4 a2 = make_float4(0.f, 0.f, 0.f, 0.f);
      float4 a3 = make_float4(0.f, 0.f, 0.f, 0.f);
      #pragma unroll
      for (int m = 0; m < NS; ++m) {
        const float4 vp = *(const float4*)&sP[m][4 * gi];
        const float4 vb = *(const float4*)&sAB[m][4 * gk];
        fma4(a0, vp.x, vb); fma4(a1, vp.y, vb);
        fma4(a2, vp.z, vb); fma4(a3, vp.w, vb);
      }
      *(float4*)&sG[4 * gi + 0][4 * gk] = a0;
      *(float4*)&sG[4 * gi + 1][4 * gk] = a1;
      *(float4*)&sG[4 * gi + 2][4 * gk] = a2;
      *(float4*)&sG[4 * gi + 3][4 * gk] = a3;
    }
    __syncthreads();

    // F[j][k] = C[j][k] + sum_m AB[m][j] * G[m][k] — outer-product 4x4 tiles
    // on the FULL sF (144 tiles, threads 0..143). C added at the end so the
    // prefetch's vmcnt wait lands after the GEMM sum.
    if (tid < 144) {
      float4 a0 = make_float4(0.f, 0.f, 0.f, 0.f);
      float4 a1 = make_float4(0.f, 0.f, 0.f, 0.f);
      float4 a2 = make_float4(0.f, 0.f, 0.f, 0.f);
      float4 a3 = make_float4(0.f, 0.f, 0.f, 0.f);
      #pragma unroll
      for (int m = 0; m < NS; ++m) {
        const float4 va = *(const float4*)&sAB[m][4 * fi];
        const float4 vg = *(const float4*)&sG[m][4 * fk];
        fma4(a0, va.x, vg); fma4(a1, va.y, vg);
        fma4(a2, va.z, vg); fma4(a3, va.w, vg);
      }
      add4(a0, cr0); add4(a1, cr1); add4(a2, cr2); add4(a3, cr3);
      *(float4*)&sF[4 * fi + 0][4 * fk] = a0;
      *(float4*)&sF[4 * fi + 1][4 * fk] = a1;
      *(float4*)&sF[4 * fi + 2][4 * fk] = a2;
      *(float4*)&sF[4 * fi + 3][4 * fk] = a3;
    }
    __syncthreads();

    // Gauss-Jordan on M = [Fuu | Fux] (16x48) in wave-0 registers.
    // [identical to r7]
    if (wid == 0) {
      const int col = (lane < 16) ? (NS + lane) : (lane - 16);
      float f[NI];
      #pragma unroll
      for (int i = 0; i < NI; ++i) f[i] = sF[NS + i][col];
      #pragma unroll
      for (int k = 0; k < NI; ++k) {
        float m[NI];
        #pragma unroll
        for (int i = 0; i < NI; ++i) m[i] = __shfl(f[i], k);
        const float inv = 1.0f / m[k];
        f[k] *= inv;
        #pragma unroll
        for (int i = 0; i < NI; ++i)
          if (i != k) f[i] -= m[i] * f[k];
      }
      if (lane >= 16 && lane < 48) {   // cols 16..47 hold K (16x32)
        const int b = lane - 16;
        #pragma unroll
        for (int i = 0; i < NI; ++i) {
          sK[i][b] = f[i];
          Kall[(size_t)t * NI * NS + i * NS + b] = f[i];
        }
      }
    }
    __syncthreads();

    // P = Fxx - Fxu @ K  (32x32 = 256 float4-blocks, one per thread)
    // [identical to r7]
    {
      int a = tid >> 3, bq = tid & 7;
      float4 acc = *(const float4*)&sF[a][4 * bq];
      #pragma unroll
      for (int i = 0; i < NI; ++i)
        fms4(acc, sF[a][NS + i], *(const float4*)&sK[i][4 * bq]);
      *(float4*)&sP[a][4 * bq] = acc;
      *((float4*)Pall + (size_t)t * 256 + tid) = acc;
    }
    __syncthreads();
  }

  // ---------------- forward rollout ----------------   [identical to r7]
  if (tid < NS) sZ[0][tid] = x0[tid];
  __syncthreads();
  for (int t = 0; t < TT; ++t) {
    if (tid < NI) {
      const float4* Kr = (const float4*)(Kall + (size_t)t * NI * NS + tid * NS);
      float acc = 0.0f;
      #pragma unroll
      for (int q = 0; q < 8; ++q) {
        float4 k4 = Kr[q];
        acc += k4.x * sZ[t][4 * q]     + k4.y * sZ[t][4 * q + 1]
             + k4.z * sZ[t][4 * q + 2] + k4.w * sZ[t][4 * q + 3];
      }
      sZ[t][NS + tid] = -acc;        // u_t = -K_t x_t
    }
    __syncthreads();
    if (t < TT - 1 && tid < NS) {
      float acc = 0.0f;
      #pragma unroll
      for (int q = 0; q < 12; ++q) {
        float4 a4 = *(const float4*)&sAB[tid][4 * q];
        acc += a4.x * sZ[t][4 * q]     + a4.y * sZ[t][4 * q + 1]
             + a4.z * sZ[t][4 * q + 2] + a4.w * sZ[t][4 * q + 3];
      }
      sZ[t + 1][tid] = acc;          // x_{t+1}
    }
    __syncthreads();
  }

  // write tau
  for (int e = tid; e < TT * NA; e += NTH) {
    int t = e / NA;
    out[e] = sZ[t][e - t * NA];
  }

  // mu_t = (t==0 ? -1 : +1) * P_t x_t  (parallel over all t)
  for (int e = tid; e < TT * NS; e += NTH) {
    int t = e >> 5, i = e & 31;
    const float4* Pr = (const float4*)(Pall + (size_t)t * NS * NS + i * NS);
    float acc = 0.0f;
    #pragma unroll
    for (int q = 0; q < 8; ++q) {
      float4 p4 = Pr[q];
      acc += p4.x * sZ[t][4 * q]     + p4.y * sZ[t][4 * q + 1]
           + p4.z * sZ[t][4 * q + 2] + p4.w * sZ[t][4 * q + 3];
    }
    out[NA * TT + e] = (t == 0) ? -acc : acc;
  }
}

} // namespace

extern "C" void kernel_launch(void* const* d_in, const int* in_sizes, int n_in,
                              void* d_out, int out_size, void* d_ws, size_t ws_size,
                              hipStream_t stream) {
  const float* A  = (const float*)d_in[0];
  const float* B  = (const float*)d_in[1];
  const float* C  = (const float*)d_in[2];
  // d_in[3] is T (==64, compile-time constant here)
  const float* x0 = (const float*)d_in[4];
  float* out  = (float*)d_out;
  float* Kall = (float*)d_ws;                        // 128 KB
  float* Pall = (float*)d_ws + (size_t)TT * NI * NS; // 256 KB

  hipLaunchKernelGGL(lqr_riccati, dim3(1), dim3(NTH), 0, stream,
                     A, B, C, x0, out, Kall, Pall);
}

// Round 9
// 284.956 us; speedup vs baseline: 1.4083x; 1.3314x over previous
//
#include <hip/hip_runtime.h>

// LQR KKT via backward Riccati + forward rollout; mu_t = P_t x_t (stable).
// Round-9 = r8 (passing, 379us) with the backward step re-phased to shorten
// the serial critical path:
//   P1: G = P^T AB            (threads 0..95, r8 form)
//   P2: Fu = u-rows of F      (threads 0..47; GJ's only dependency)
//   P3: wave0 Gauss-Jordan (readlane + rcp, off the DS pipe)
//       || threads 64..159: Fxx+Fxu (x-rows of F)   <- overlap
//   P4: P-update              (r8 form, all 256 threads)
// Rollout / tau / mu byte-identical to r8. Full sF[48][48] retained.
//
// Dims: n_state=32, n_input=16, n_all=48, T=64.

namespace {

constexpr int NS  = 32;
constexpr int NI  = 16;
constexpr int NA  = 48;
constexpr int TT  = 64;
constexpr int NTH = 256;

__device__ __forceinline__ void fma4(float4& a, float s, const float4& b) {
  a.x += s * b.x; a.y += s * b.y; a.z += s * b.z; a.w += s * b.w;
}
__device__ __forceinline__ void fms4(float4& a, float s, const float4& b) {
  a.x -= s * b.x; a.y -= s * b.y; a.z -= s * b.z; a.w -= s * b.w;
}
__device__ __forceinline__ void add4(float4& a, const float4& b) {
  a.x += b.x; a.y += b.y; a.z += b.z; a.w += b.w;
}
__device__ __forceinline__ float rdlane(float v, int l) {
  return __int_as_float(__builtin_amdgcn_readlane(__float_as_int(v), l));
}

__global__ __launch_bounds__(NTH, 1) void lqr_riccati(
    const float* __restrict__ A,
    const float* __restrict__ Bm,
    const float* __restrict__ C,     // [TT][NA][NA]
    const float* __restrict__ x0,
    float* __restrict__ out,         // [TT*NA] tau then [TT*NS] mu
    float* __restrict__ Kall,        // scratch: TT*NI*NS floats
    float* __restrict__ Pall)        // scratch: TT*NS*NS floats
{
  __shared__ float sAB[NS][NA];   // [A | B]
  __shared__ float sP [NS][NS];   // P_{t+1}
  __shared__ float sG [NS][NA];   // P^T @ [A B]
  __shared__ float sF [NA][NA];   // C_t + [A B]^T G
  __shared__ float sK [NI][NS];   // K_t
  __shared__ float sZ [TT][NA];   // trajectory z_t = (x_t, u_t)

  const int tid  = threadIdx.x;
  const int lane = tid & 63;
  const int wid  = tid >> 6;

  // stage [A | B], zero P
  for (int e = tid; e < NS * NA; e += NTH) {
    int i = e / NA, j = e - i * NA;
    sAB[i][j] = (j < NS) ? A[i * NS + j] : Bm[i * NI + (j - NS)];
  }
  for (int e = tid; e < NS * NS; e += NTH) sP[e >> 5][e & 31] = 0.0f;
  __syncthreads();

  // loop-invariant tile coordinates
  const int ui = tid / 12,          uk = tid - 12 * ui;          // Fu tiles (tid<48)
  const int xq = tid - 64;
  const int xi = xq / 12,           xk = xq - 12 * xi;           // Fxx tiles (64<=tid<160)

  // ---------------- backward Riccati ----------------
  for (int t = TT - 1; t >= 0; --t) {
    const float* Ct = C + (size_t)t * NA * NA;

    // Per-tile C prefetch (consumed in P2/P3; latency hides under G).
    float4 cr0 = make_float4(0.f, 0.f, 0.f, 0.f);
    float4 cr1 = make_float4(0.f, 0.f, 0.f, 0.f);
    float4 cr2 = make_float4(0.f, 0.f, 0.f, 0.f);
    float4 cr3 = make_float4(0.f, 0.f, 0.f, 0.f);
    if (tid < 48) {                       // my Fu tile: rows NS+4ui.., cols 4uk
      cr0 = *(const float4*)&Ct[(NS + 4 * ui + 0) * NA + 4 * uk];
      cr1 = *(const float4*)&Ct[(NS + 4 * ui + 1) * NA + 4 * uk];
      cr2 = *(const float4*)&Ct[(NS + 4 * ui + 2) * NA + 4 * uk];
      cr3 = *(const float4*)&Ct[(NS + 4 * ui + 3) * NA + 4 * uk];
    } else if (tid >= 64 && tid < 160) {  // my Fxx tile: rows 4xi.., cols 4xk
      cr0 = *(const float4*)&Ct[(4 * xi + 0) * NA + 4 * xk];
      cr1 = *(const float4*)&Ct[(4 * xi + 1) * NA + 4 * xk];
      cr2 = *(const float4*)&Ct[(4 * xi + 2) * NA + 4 * xk];
      cr3 = *(const float4*)&Ct[(4 * xi + 3) * NA + 4 * xk];
    }

    // ---- P1: G[i][k] = sum_m P[m][i] * AB[m][k]  (96 4x4 tiles) [r8 form]
    if (tid < 96) {
      const int gi = tid / 12, gk = tid - 12 * gi;
      float4 a0 = make_float4(0.f, 0.f, 0.f, 0.f);
      float4 a1 = make_float4(0.f, 0.f, 0.f, 0.f);
      float4 a2 = make_float4(0.f, 0.f, 0.f, 0.f);
      float4 a3 = make_float4(0.f, 0.f, 0.f, 0.f);
      #pragma unroll
      for (int m = 0; m < NS; ++m) {
        const float4 vp = *(const float4*)&sP[m][4 * gi];
        const float4 vb = *(const float4*)&sAB[m][4 * gk];
        fma4(a0, vp.x, vb); fma4(a1, vp.y, vb);
        fma4(a2, vp.z, vb); fma4(a3, vp.w, vb);
      }
      *(float4*)&sG[4 * gi + 0][4 * gk] = a0;
      *(float4*)&sG[4 * gi + 1][4 * gk] = a1;
      *(float4*)&sG[4 * gi + 2][4 * gk] = a2;
      *(float4*)&sG[4 * gi + 3][4 * gk] = a3;
    }
    __syncthreads();

    // ---- P2: Fu (u-rows of F only; GJ's dependency)  (48 tiles, tid<48)
    if (tid < 48) {
      float4 a0 = make_float4(0.f, 0.f, 0.f, 0.f);
      float4 a1 = make_float4(0.f, 0.f, 0.f, 0.f);
      float4 a2 = make_float4(0.f, 0.f, 0.f, 0.f);
      float4 a3 = make_float4(0.f, 0.f, 0.f, 0.f);
      #pragma unroll
      for (int m = 0; m < NS; ++m) {
        const float4 va = *(const float4*)&sAB[m][NS + 4 * ui];
        const float4 vg = *(const float4*)&sG[m][4 * uk];
        fma4(a0, va.x, vg); fma4(a1, va.y, vg);
        fma4(a2, va.z, vg); fma4(a3, va.w, vg);
      }
      add4(a0, cr0); add4(a1, cr1); add4(a2, cr2); add4(a3, cr3);
      *(float4*)&sF[NS + 4 * ui + 0][4 * uk] = a0;
      *(float4*)&sF[NS + 4 * ui + 1][4 * uk] = a1;
      *(float4*)&sF[NS + 4 * ui + 2][4 * uk] = a2;
      *(float4*)&sF[NS + 4 * ui + 3][4 * uk] = a3;
    }
    __syncthreads();

    // ---- P3: wave0 Gauss-Jordan (readlane + rcp, off DS pipe)
    //          || threads 64..159: Fxx+Fxu (x-rows of F)
    if (wid == 0) {
      // lane c: c<16 -> Fuu col c (sF col 32+c), c in 16..47 -> x-col c-16.
      // lanes 48-63 compute garbage on valid addresses, never write.
      const int col = (lane < 16) ? (NS + lane) : (lane - 16);
      float f[NI];
      #pragma unroll
      for (int i = 0; i < NI; ++i) f[i] = sF[NS + i][col];
      #pragma unroll
      for (int k = 0; k < NI; ++k) {
        float mi[NI];
        #pragma unroll
        for (int i = 0; i < NI; ++i) mi[i] = rdlane(f[i], k);
        const float inv = __builtin_amdgcn_rcpf(mi[k]);
        f[k] *= inv;
        #pragma unroll
        for (int i = 0; i < NI; ++i)
          if (i != k) f[i] -= mi[i] * f[k];
      }
      if (lane >= 16 && lane < 48) {   // cols 16..47 hold K (16x32)
        const int b = lane - 16;
        #pragma unroll
        for (int i = 0; i < NI; ++i) {
          sK[i][b] = f[i];
          Kall[(size_t)t * NI * NS + i * NS + b] = f[i];
        }
      }
    } else if (tid >= 64 && tid < 160) {
      float4 a0 = make_float4(0.f, 0.f, 0.f, 0.f);
      float4 a1 = make_float4(0.f, 0.f, 0.f, 0.f);
      float4 a2 = make_float4(0.f, 0.f, 0.f, 0.f);
      float4 a3 = make_float4(0.f, 0.f, 0.f, 0.f);
      #pragma unroll
      for (int m = 0; m < NS; ++m) {
        const float4 va = *(const float4*)&sAB[m][4 * xi];
        const float4 vg = *(const float4*)&sG[m][4 * xk];
        fma4(a0, va.x, vg); fma4(a1, va.y, vg);
        fma4(a2, va.z, vg); fma4(a3, va.w, vg);
      }
      add4(a0, cr0); add4(a1, cr1); add4(a2, cr2); add4(a3, cr3);
      *(float4*)&sF[4 * xi + 0][4 * xk] = a0;
      *(float4*)&sF[4 * xi + 1][4 * xk] = a1;
      *(float4*)&sF[4 * xi + 2][4 * xk] = a2;
      *(float4*)&sF[4 * xi + 3][4 * xk] = a3;
    }
    __syncthreads();

    // ---- P4: P = Fxx - Fxu @ K  (256 float4-blocks, one per thread) [r8 form]
    {
      int a = tid >> 3, bq = tid & 7;
      float4 acc = *(const float4*)&sF[a][4 * bq];
      #pragma unroll
      for (int i = 0; i < NI; ++i)
        fms4(acc, sF[a][NS + i], *(const float4*)&sK[i][4 * bq]);
      *(float4*)&sP[a][4 * bq] = acc;
      *((float4*)Pall + (size_t)t * 256 + tid) = acc;
    }
    __syncthreads();
  }

  // ---------------- forward rollout ----------------   [identical to r8]
  if (tid < NS) sZ[0][tid] = x0[tid];
  __syncthreads();
  for (int t = 0; t < TT; ++t) {
    if (tid < NI) {
      const float4* Kr = (const float4*)(Kall + (size_t)t * NI * NS + tid * NS);
      float acc = 0.0f;
      #pragma unroll
      for (int q = 0; q < 8; ++q) {
        float4 k4 = Kr[q];
        acc += k4.x * sZ[t][4 * q]     + k4.y * sZ[t][4 * q + 1]
             + k4.z * sZ[t][4 * q + 2] + k4.w * sZ[t][4 * q + 3];
      }
      sZ[t][NS + tid] = -acc;        // u_t = -K_t x_t
    }
    __syncthreads();
    if (t < TT - 1 && tid < NS) {
      float acc = 0.0f;
      #pragma unroll
      for (int q = 0; q < 12; ++q) {
        float4 a4 = *(const float4*)&sAB[tid][4 * q];
        acc += a4.x * sZ[t][4 * q]     + a4.y * sZ[t][4 * q + 1]
             + a4.z * sZ[t][4 * q + 2] + a4.w * sZ[t][4 * q + 3];
      }
      sZ[t + 1][tid] = acc;          // x_{t+1}
    }
    __syncthreads();
  }

  // write tau
  for (int e = tid; e < TT * NA; e += NTH) {
    int t = e / NA;
    out[e] = sZ[t][e - t * NA];
  }

  // mu_t = (t==0 ? -1 : +1) * P_t x_t  (parallel over all t)
  for (int e = tid; e < TT * NS; e += NTH) {
    int t = e >> 5, i = e & 31;
    const float4* Pr = (const float4*)(Pall + (size_t)t * NS * NS + i * NS);
    float acc = 0.0f;
    #pragma unroll
    for (int q = 0; q < 8; ++q) {
      float4 p4 = Pr[q];
      acc += p4.x * sZ[t][4 * q]     + p4.y * sZ[t][4 * q + 1]
           + p4.z * sZ[t][4 * q + 2] + p4.w * sZ[t][4 * q + 3];
    }
    out[NA * TT + e] = (t == 0) ? -acc : acc;
  }
}

} // namespace

extern "C" void kernel_launch(void* const* d_in, const int* in_sizes, int n_in,
                              void* d_out, int out_size, void* d_ws, size_t ws_size,
                              hipStream_t stream) {
  const float* A  = (const float*)d_in[0];
  const float* B  = (const float*)d_in[1];
  const float* C  = (const float*)d_in[2];
  // d_in[3] is T (==64, compile-time constant here)
  const float* x0 = (const float*)d_in[4];
  float* out  = (float*)d_out;
  float* Kall = (float*)d_ws;                        // 128 KB
  float* Pall = (float*)d_ws + (size_t)TT * NI * NS; // 256 KB

  hipLaunchKernelGGL(lqr_riccati, dim3(1), dim3(NTH), 0, stream,
                     A, B, C, x0, out, Kall, Pall);
}

// Round 10
// 277.504 us; speedup vs baseline: 1.4461x; 1.0269x over previous
//
#include <hip/hip_runtime.h>

// LQR KKT via backward Riccati + forward rollout; mu_t = P_t x_t (stable).
// Round-10: critical-path restructure.
//   Backward (3 barriers/step):
//     PhA: F = C_t + AB^T G                 (144 4x4 tiles, threads 0..143)
//     PhB: GJ on wave0  ||  U = Fx^T AB     (144 tiles, threads 64..207)
//     PhC: G' = U_x - K^T U_u (threads 0..95)  [= (Fxx - Fxu K)^T AB exactly]
//          || M = A - B K -> Mall (96..159) || P = Fxx - Fxu K -> Pall (160..223)
//   Forward: x_{t+1} = M_t x_t — single-wave, ZERO barriers, M double-buffered
//   u-pass:  u_t = -K_t x_t  (parallel over all t)
//   mu-pass: mu_t = P_t x_t  (parallel; mu_0 = -P_0 x_0)
// Dims: n_state=32, n_input=16, n_all=48, T=64.

namespace {

constexpr int NS  = 32;
constexpr int NI  = 16;
constexpr int NA  = 48;
constexpr int TT  = 64;
constexpr int NTH = 256;

__device__ __forceinline__ void fma4(float4& a, float s, const float4& b) {
  a.x += s * b.x; a.y += s * b.y; a.z += s * b.z; a.w += s * b.w;
}
__device__ __forceinline__ void fms4(float4& a, float s, const float4& b) {
  a.x -= s * b.x; a.y -= s * b.y; a.z -= s * b.z; a.w -= s * b.w;
}
__device__ __forceinline__ void add4(float4& a, const float4& b) {
  a.x += b.x; a.y += b.y; a.z += b.z; a.w += b.w;
}
__device__ __forceinline__ float dot4(const float4& a, const float4& b) {
  return a.x * b.x + a.y * b.y + a.z * b.z + a.w * b.w;
}
__device__ __forceinline__ float rdlane(float v, int l) {
  return __int_as_float(__builtin_amdgcn_readlane(__float_as_int(v), l));
}

__global__ __launch_bounds__(NTH, 1) void lqr_riccati(
    const float* __restrict__ A,
    const float* __restrict__ Bm,
    const float* __restrict__ C,     // [TT][NA][NA]
    const float* __restrict__ x0,
    float* __restrict__ out,         // [TT*NA] tau then [TT*NS] mu
    float* __restrict__ Kall,        // ws: TT*NI*NS floats
    float* __restrict__ Pall,        // ws: TT*NS*NS floats
    float* __restrict__ Mall)        // ws: TT*NS*NS floats
{
  __shared__ float sAB[NS][NA];    // [A | B]
  __shared__ float sG [NS][NA];    // G = P_{t+1}^T AB (maintained directly)
  __shared__ float sF [NA][NA];    // C_t + AB^T G
  __shared__ float sU [NA][NA];    // U = Fx^T AB
  __shared__ float sK [NI][NS];    // K_t
  __shared__ float sZx[TT][NS];    // x trajectory
  __shared__ float sMb[2 * NS * NS]; // rollout M double buffer

  const int tid  = threadIdx.x;
  const int lane = tid & 63;
  const int wid  = tid >> 6;

  // stage [A | B]; zero G (P_T = 0)
  for (int e = tid; e < NS * NA; e += NTH) {
    int i = e / NA, j = e - i * NA;
    sAB[i][j] = (j < NS) ? A[i * NS + j] : Bm[i * NI + (j - NS)];
    sG[i][j] = 0.0f;
  }
  __syncthreads();

  // loop-invariant tile coords
  const int fi = tid / 12, fk = tid - 12 * fi;          // PhA tiles (tid<144)
  const int uq = tid - 64;
  const int ui = uq / 12, uk = uq - 12 * ui;            // PhB U tiles (64<=tid<208)
  const int mq = tid - 96, ma = mq >> 3, mb = mq & 7;   // PhC M tiles (96..159)
  const int pq = tid - 160, pa = pq >> 3, pb = pq & 7;  // PhC P tiles (160..223)

  // ---------------- backward Riccati ----------------
  for (int t = TT - 1; t >= 0; --t) {
    const float* Ct = C + (size_t)t * NA * NA;

    // C prefetch for my F tile (hides under PhA's own GEMM; C added last)
    float4 cr0 = make_float4(0.f, 0.f, 0.f, 0.f);
    float4 cr1 = make_float4(0.f, 0.f, 0.f, 0.f);
    float4 cr2 = make_float4(0.f, 0.f, 0.f, 0.f);
    float4 cr3 = make_float4(0.f, 0.f, 0.f, 0.f);
    if (tid < 144) {
      cr0 = *(const float4*)&Ct[(4 * fi + 0) * NA + 4 * fk];
      cr1 = *(const float4*)&Ct[(4 * fi + 1) * NA + 4 * fk];
      cr2 = *(const float4*)&Ct[(4 * fi + 2) * NA + 4 * fk];
      cr3 = *(const float4*)&Ct[(4 * fi + 3) * NA + 4 * fk];
    }

    // ---- PhA: F[j][k] = C[j][k] + sum_m AB[m][j] * G[m][k]  (full 48x48)
    if (tid < 144) {
      float4 a0 = make_float4(0.f, 0.f, 0.f, 0.f);
      float4 a1 = make_float4(0.f, 0.f, 0.f, 0.f);
      float4 a2 = make_float4(0.f, 0.f, 0.f, 0.f);
      float4 a3 = make_float4(0.f, 0.f, 0.f, 0.f);
      #pragma unroll
      for (int m = 0; m < NS; ++m) {
        const float4 va = *(const float4*)&sAB[m][4 * fi];
        const float4 vg = *(const float4*)&sG[m][4 * fk];
        fma4(a0, va.x, vg); fma4(a1, va.y, vg);
        fma4(a2, va.z, vg); fma4(a3, va.w, vg);
      }
      add4(a0, cr0); add4(a1, cr1); add4(a2, cr2); add4(a3, cr3);
      *(float4*)&sF[4 * fi + 0][4 * fk] = a0;
      *(float4*)&sF[4 * fi + 1][4 * fk] = a1;
      *(float4*)&sF[4 * fi + 2][4 * fk] = a2;
      *(float4*)&sF[4 * fi + 3][4 * fk] = a3;
    }
    __syncthreads();

    // ---- PhB: wave0 Gauss-Jordan (readlane+rcp, r9-proven)
    //           || U[c][k] = sum_a F[a][c] * AB[a][k]  (threads 64..207)
    if (wid == 0) {
      const int col = (lane < 16) ? (NS + lane) : (lane - 16);
      float f[NI];
      #pragma unroll
      for (int i = 0; i < NI; ++i) f[i] = sF[NS + i][col];
      #pragma unroll
      for (int k = 0; k < NI; ++k) {
        float mi[NI];
        #pragma unroll
        for (int i = 0; i < NI; ++i) mi[i] = rdlane(f[i], k);
        const float inv = __builtin_amdgcn_rcpf(mi[k]);
        f[k] *= inv;
        #pragma unroll
        for (int i = 0; i < NI; ++i)
          if (i != k) f[i] -= mi[i] * f[k];
      }
      if (lane >= 16 && lane < 48) {   // cols 16..47 hold K (16x32)
        const int b = lane - 16;
        #pragma unroll
        for (int i = 0; i < NI; ++i) {
          sK[i][b] = f[i];
          Kall[(size_t)t * NI * NS + i * NS + b] = f[i];
        }
      }
    } else if (tid < 208) {
      float4 a0 = make_float4(0.f, 0.f, 0.f, 0.f);
      float4 a1 = make_float4(0.f, 0.f, 0.f, 0.f);
      float4 a2 = make_float4(0.f, 0.f, 0.f, 0.f);
      float4 a3 = make_float4(0.f, 0.f, 0.f, 0.f);
      #pragma unroll
      for (int a = 0; a < NS; ++a) {
        const float4 vf = *(const float4*)&sF[a][4 * ui];
        const float4 vb = *(const float4*)&sAB[a][4 * uk];
        fma4(a0, vf.x, vb); fma4(a1, vf.y, vb);
        fma4(a2, vf.z, vb); fma4(a3, vf.w, vb);
      }
      *(float4*)&sU[4 * ui + 0][4 * uk] = a0;
      *(float4*)&sU[4 * ui + 1][4 * uk] = a1;
      *(float4*)&sU[4 * ui + 2][4 * uk] = a2;
      *(float4*)&sU[4 * ui + 3][4 * uk] = a3;
    }
    __syncthreads();

    // ---- PhC: G' (0..95) || M -> Mall (96..159) || P -> Pall (160..223)
    if (tid < 96) {
      // G'[i][k] = U[i][k] - sum_j K[j][i] * U[NS+j][k]
      const int gi = tid / 12, gk = tid - 12 * (tid / 12);
      float4 a0 = *(const float4*)&sU[4 * gi + 0][4 * gk];
      float4 a1 = *(const float4*)&sU[4 * gi + 1][4 * gk];
      float4 a2 = *(const float4*)&sU[4 * gi + 2][4 * gk];
      float4 a3 = *(const float4*)&sU[4 * gi + 3][4 * gk];
      #pragma unroll
      for (int j = 0; j < NI; ++j) {
        const float4 vk = *(const float4*)&sK[j][4 * gi];
        const float4 vu = *(const float4*)&sU[NS + j][4 * gk];
        fms4(a0, vk.x, vu); fms4(a1, vk.y, vu);
        fms4(a2, vk.z, vu); fms4(a3, vk.w, vu);
      }
      *(float4*)&sG[4 * gi + 0][4 * gk] = a0;
      *(float4*)&sG[4 * gi + 1][4 * gk] = a1;
      *(float4*)&sG[4 * gi + 2][4 * gk] = a2;
      *(float4*)&sG[4 * gi + 3][4 * gk] = a3;
    } else if (tid < 160) {
      // M[a][b] = AB[a][b] - sum_i AB[a][NS+i] * K[i][b]
      float4 a0 = *(const float4*)&sAB[4 * ma + 0][4 * mb];
      float4 a1 = *(const float4*)&sAB[4 * ma + 1][4 * mb];
      float4 a2 = *(const float4*)&sAB[4 * ma + 2][4 * mb];
      float4 a3 = *(const float4*)&sAB[4 * ma + 3][4 * mb];
      #pragma unroll
      for (int q = 0; q < 4; ++q) {
        const float4 vf0 = *(const float4*)&sAB[4 * ma + 0][NS + 4 * q];
        const float4 vf1 = *(const float4*)&sAB[4 * ma + 1][NS + 4 * q];
        const float4 vf2 = *(const float4*)&sAB[4 * ma + 2][NS + 4 * q];
        const float4 vf3 = *(const float4*)&sAB[4 * ma + 3][NS + 4 * q];
        #pragma unroll
        for (int d = 0; d < 4; ++d) {
          const float4 vkk = *(const float4*)&sK[4 * q + d][4 * mb];
          const float s0 = (d == 0) ? vf0.x : (d == 1) ? vf0.y : (d == 2) ? vf0.z : vf0.w;
          const float s1 = (d == 0) ? vf1.x : (d == 1) ? vf1.y : (d == 2) ? vf1.z : vf1.w;
          const float s2 = (d == 0) ? vf2.x : (d == 1) ? vf2.y : (d == 2) ? vf2.z : vf2.w;
          const float s3 = (d == 0) ? vf3.x : (d == 1) ? vf3.y : (d == 2) ? vf3.z : vf3.w;
          fms4(a0, s0, vkk); fms4(a1, s1, vkk); fms4(a2, s2, vkk); fms4(a3, s3, vkk);
        }
      }
      float4* Mt = (float4*)(Mall + (size_t)t * NS * NS);
      Mt[(4 * ma + 0) * 8 + mb] = a0;
      Mt[(4 * ma + 1) * 8 + mb] = a1;
      Mt[(4 * ma + 2) * 8 + mb] = a2;
      Mt[(4 * ma + 3) * 8 + mb] = a3;
    } else if (tid < 224) {
      // P[a][b] = F[a][b] - sum_i F[a][NS+i] * K[i][b]
      float4 a0 = *(const float4*)&sF[4 * pa + 0][4 * pb];
      float4 a1 = *(const float4*)&sF[4 * pa + 1][4 * pb];
      float4 a2 = *(const float4*)&sF[4 * pa + 2][4 * pb];
      float4 a3 = *(const float4*)&sF[4 * pa + 3][4 * pb];
      #pragma unroll
      for (int q = 0; q < 4; ++q) {
        const float4 vf0 = *(const float4*)&sF[4 * pa + 0][NS + 4 * q];
        const float4 vf1 = *(const float4*)&sF[4 * pa + 1][NS + 4 * q];
        const float4 vf2 = *(const float4*)&sF[4 * pa + 2][NS + 4 * q];
        const float4 vf3 = *(const float4*)&sF[4 * pa + 3][NS + 4 * q];
        #pragma unroll
        for (int d = 0; d < 4; ++d) {
          const float4 vkk = *(const float4*)&sK[4 * q + d][4 * pb];
          const float s0 = (d == 0) ? vf0.x : (d == 1) ? vf0.y : (d == 2) ? vf0.z : vf0.w;
          const float s1 = (d == 0) ? vf1.x : (d == 1) ? vf1.y : (d == 2) ? vf1.z : vf1.w;
          const float s2 = (d == 0) ? vf2.x : (d == 1) ? vf2.y : (d == 2) ? vf2.z : vf2.w;
          const float s3 = (d == 0) ? vf3.x : (d == 1) ? vf3.y : (d == 2) ? vf3.z : vf3.w;
          fms4(a0, s0, vkk); fms4(a1, s1, vkk); fms4(a2, s2, vkk); fms4(a3, s3, vkk);
        }
      }
      float4* Pt = (float4*)(Pall + (size_t)t * NS * NS);
      Pt[(4 * pa + 0) * 8 + pb] = a0;
      Pt[(4 * pa + 1) * 8 + pb] = a1;
      Pt[(4 * pa + 2) * 8 + pb] = a2;
      Pt[(4 * pa + 3) * 8 + pb] = a3;
    }
    __syncthreads();
  }

  // ---------------- forward rollout: x_{t+1} = M_t x_t (wave0, 0 barriers) --
  if (wid == 0) {
    const float4* M4 = (const float4*)Mall;
    float4* sM4 = (float4*)sMb;
    if (lane < NS) { float v = x0[lane]; sZx[0][lane] = v; out[lane] = v; }
    // load M_0 into buffer 0 (4 float4 per lane)
    float4 p0 = M4[lane], p1 = M4[64 + lane], p2 = M4[128 + lane], p3 = M4[192 + lane];
    asm volatile("s_waitcnt vmcnt(0)" ::: "memory");
    sM4[lane] = p0; sM4[64 + lane] = p1; sM4[128 + lane] = p2; sM4[192 + lane] = p3;
    asm volatile("s_waitcnt lgkmcnt(0)" ::: "memory");
    __builtin_amdgcn_sched_barrier(0);
    int cur = 0;
    for (int t = 0; t < TT - 1; ++t) {
      const bool pf = (t + 1 < TT - 1);
      if (pf) {
        const int b = (t + 1) * 256;
        p0 = M4[b + lane]; p1 = M4[b + 64 + lane];
        p2 = M4[b + 128 + lane]; p3 = M4[b + 192 + lane];
      }
      if (lane < NS) {
        const float4* xr = (const float4*)&sZx[t][0];
        const float4* mr = sM4 + cur * 256 + 8 * lane;
        float acc = 0.0f;
        #pragma unroll
        for (int q = 0; q < 8; ++q) acc += dot4(mr[q], xr[q]);
        sZx[t + 1][lane] = acc;
        out[(t + 1) * NA + lane] = acc;
      }
      if (pf) {
        asm volatile("s_waitcnt vmcnt(0)" ::: "memory");
        float4* d = sM4 + (cur ^ 1) * 256;
        d[lane] = p0; d[64 + lane] = p1; d[128 + lane] = p2; d[192 + lane] = p3;
      }
      asm volatile("s_waitcnt lgkmcnt(0)" ::: "memory");
      __builtin_amdgcn_sched_barrier(0);
      cur ^= 1;
    }
  }
  __syncthreads();

  // ---------------- u-pass: u_t = -K_t x_t  (parallel, 4 outputs/thread) ----
  const float4* K4 = (const float4*)Kall;
  #pragma unroll
  for (int rep = 0; rep < 4; ++rep) {
    const int idx = tid + 256 * rep;       // 0..1023
    const int t = idx >> 4, i = idx & 15;
    const float4* xr = (const float4*)&sZx[t][0];
    float acc = 0.0f;
    #pragma unroll
    for (int q = 0; q < 8; ++q) acc += dot4(K4[(size_t)t * 128 + 8 * i + q], xr[q]);
    out[t * NA + NS + i] = -acc;
  }

  // ---------------- mu-pass: mu_t = (t==0?-1:+1) * P_t x_t ----------------
  const float4* P4 = (const float4*)Pall;
  for (int e = tid; e < TT * NS; e += NTH) {
    const int t = e >> 5, i = e & 31;
    const float4* xr = (const float4*)&sZx[t][0];
    float acc = 0.0f;
    #pragma unroll
    for (int q = 0; q < 8; ++q) acc += dot4(P4[(size_t)t * 256 + 8 * i + q], xr[q]);
    out[NA * TT + e] = (t == 0) ? -acc : acc;
  }
}

} // namespace

extern "C" void kernel_launch(void* const* d_in, const int* in_sizes, int n_in,
                              void* d_out, int out_size, void* d_ws, size_t ws_size,
                              hipStream_t stream) {
  const float* A  = (const float*)d_in[0];
  const float* B  = (const float*)d_in[1];
  const float* C  = (const float*)d_in[2];
  // d_in[3] is T (==64, compile-time constant here)
  const float* x0 = (const float*)d_in[4];
  float* out  = (float*)d_out;
  float* Kall = (float*)d_ws;                                   // 128 KB
  float* Pall = Kall + (size_t)TT * NI * NS;                    // 256 KB
  float* Mall = Pall + (size_t)TT * NS * NS;                    // 256 KB

  hipLaunchKernelGGL(lqr_riccati, dim3(1), dim3(NTH), 0, stream,
                     A, B, C, x0, out, Kall, Pall, Mall);
}

// Round 11
// 137.957 us; speedup vs baseline: 2.9090x; 2.0115x over previous
//
#include <hip/hip_runtime.h>

// LQR KKT via TEMPORALLY-PARALLEL Riccati (associative suffix scan, info form)
// + parallel K/M extraction + r10-proven rollout/u/mu tail.
//
//   element init (per t, parallel): J_e = Q - S R^-1 S^T, A_e = A - B R^-1 S^T,
//                                   C_e = B R^-1 B^T
//   combine (i=earlier, j=later):   T1 = (I + C_i J_j)^-1
//                                   A' = A_j T1 A_i
//                                   C' = A_j T1 C_i A_j^T + C_j
//                                   J' = A_i^T (J_j T1) A_i + J_i
//   suffix scan (6 levels, off=1,2,4,8,16,32):  S_t = e_t (x) ... (x) e_{T-1}
//   P_t = J(S_t);  K_t from P_{t+1} via proven G->Fu->GJ16;  M_t = A - B K_t
//   rollout x_{t+1} = M_t x_t (1 wave);  u_t = -K_t x_t;  mu_t = +/- P_t x_t
//
// Dims: n_state=32, n_input=16, n_all=48, T=64.  Fallback anchor: r10 (277us).

namespace {

constexpr int NS  = 32;
constexpr int NI  = 16;
constexpr int NA  = 48;
constexpr int TT  = 64;
constexpr int NTH = 256;

__device__ __forceinline__ void fma4(float4& a, float s, const float4& b) {
  a.x += s * b.x; a.y += s * b.y; a.z += s * b.z; a.w += s * b.w;
}
__device__ __forceinline__ void fms4(float4& a, float s, const float4& b) {
  a.x -= s * b.x; a.y -= s * b.y; a.z -= s * b.z; a.w -= s * b.w;
}
__device__ __forceinline__ float dot4(const float4& a, const float4& b) {
  return a.x * b.x + a.y * b.y + a.z * b.z + a.w * b.w;
}
__device__ __forceinline__ float rdlane(float v, int l) {
  return __int_as_float(__builtin_amdgcn_readlane(__float_as_int(v), l));
}

// D-tile(4x4) += sum_m A[m][a0..a0+3] (outer) B[m][b0..b0+3]; A,B row-major LDS.
template<int K>
__device__ __forceinline__ void tile_outer(const float* Acol0, int lda,
                                           const float* Bcol0, int ldb,
                                           float4 acc[4]) {
  #pragma unroll
  for (int m = 0; m < K; ++m) {
    const float4 va = *(const float4*)(Acol0 + m * lda);
    const float4 vb = *(const float4*)(Bcol0 + m * ldb);
    fma4(acc[0], va.x, vb); fma4(acc[1], va.y, vb);
    fma4(acc[2], va.z, vb); fma4(acc[3], va.w, vb);
  }
}

// acc[r][c] += dot over 4*KQ of A-row(r) and B-row(c)  (computes A . B^T tile)
template<int KQ>
__device__ __forceinline__ void tile_dot(const float* Arow0, int lda,
                                         const float* Brow0, int ldb,
                                         float acc[4][4]) {
  #pragma unroll
  for (int q = 0; q < KQ; ++q) {
    float4 va[4], vb[4];
    #pragma unroll
    for (int r = 0; r < 4; ++r) va[r] = *(const float4*)(Arow0 + r * lda + 4 * q);
    #pragma unroll
    for (int c = 0; c < 4; ++c) vb[c] = *(const float4*)(Brow0 + c * ldb + 4 * q);
    #pragma unroll
    for (int r = 0; r < 4; ++r)
      #pragma unroll
      for (int c = 0; c < 4; ++c) acc[r][c] += dot4(va[r], vb[c]);
  }
}

// ---------------- kernel 1: per-step element init (grid = TT) ----------------
__global__ __launch_bounds__(NTH, 1) void init_elems(
    const float* __restrict__ A, const float* __restrict__ Bm,
    const float* __restrict__ C, float* __restrict__ S0) {
  __shared__ float sC [NA][NA];
  __shared__ float sAB[NS][NA];
  __shared__ float sRi[NI][NI];    // R^{-1} (symmetric)
  __shared__ float sRiST[NS][NI];  // S R^{-1}
  __shared__ float sBRi [NS][NI];  // B R^{-1}
  const int t = blockIdx.x, tid = threadIdx.x, lane = tid & 63, wid = tid >> 6;
  const float* Ct = C + (size_t)t * NA * NA;

  for (int e = tid; e < NA * NA; e += NTH) sC[e / NA][e % NA] = Ct[e];
  for (int e = tid; e < NS * NA; e += NTH) {
    int i = e / NA, j = e % NA;
    sAB[i][j] = (j < NS) ? A[i * NS + j] : Bm[i * NI + (j - NS)];
  }
  __syncthreads();

  // GJ16: invert R = C[32:48,32:48] (SPD). lanes 0..31: [R | I].
  if (wid == 0 && lane < 32) {
    const int c = lane;
    float f[NI];
    #pragma unroll
    for (int i = 0; i < NI; ++i)
      f[i] = (c < NI) ? sC[NS + i][NS + c] : ((c - NI) == i ? 1.f : 0.f);
    #pragma unroll
    for (int k = 0; k < NI; ++k) {
      float mi[NI];
      #pragma unroll
      for (int i = 0; i < NI; ++i) mi[i] = rdlane(f[i], k);
      const float inv = 1.0f / mi[k];
      f[k] *= inv;
      #pragma unroll
      for (int i = 0; i < NI; ++i) if (i != k) f[i] -= mi[i] * f[k];
    }
    if (c >= NI) {
      #pragma unroll
      for (int i = 0; i < NI; ++i) sRi[i][c - NI] = f[i];
    }
  }
  __syncthreads();

  // RiST = S·R^{-1} (32x16; dot S-rows x Rinv-rows, R^{-1} sym)  thr 0..31
  // BRi  = B·R^{-1} (32x16)                                      thr 32..63
  if (tid < 32) {
    const int a = tid >> 2, b = tid & 3;
    float acc[4][4];
    #pragma unroll
    for (int r = 0; r < 4; ++r)
      #pragma unroll
      for (int c = 0; c < 4; ++c) acc[r][c] = 0.f;
    tile_dot<4>(&sC[4 * a][NS], NA, &sRi[4 * b][0], NI, acc);
    #pragma unroll
    for (int r = 0; r < 4; ++r)
      *(float4*)&sRiST[4 * a + r][4 * b] =
          make_float4(acc[r][0], acc[r][1], acc[r][2], acc[r][3]);
  } else if (tid < 64) {
    const int q = tid - 32, a = q >> 2, b = q & 3;
    float acc[4][4];
    #pragma unroll
    for (int r = 0; r < 4; ++r)
      #pragma unroll
      for (int c = 0; c < 4; ++c) acc[r][c] = 0.f;
    tile_dot<4>(&sAB[4 * a][NS], NA, &sRi[4 * b][0], NI, acc);
    #pragma unroll
    for (int r = 0; r < 4; ++r)
      *(float4*)&sBRi[4 * a + r][4 * b] =
          make_float4(acc[r][0], acc[r][1], acc[r][2], acc[r][3]);
  }
  __syncthreads();

  float* outA = S0 + (size_t)t * 3072;
  float* outC = outA + 1024;
  float* outJ = outA + 2048;
  if (tid < 64) {            // J_e = Q - RiST·S^T
    const int a = tid >> 3, b = tid & 7;
    float acc[4][4];
    #pragma unroll
    for (int r = 0; r < 4; ++r)
      #pragma unroll
      for (int c = 0; c < 4; ++c) acc[r][c] = 0.f;
    tile_dot<4>(&sRiST[4 * a][0], NI, &sC[4 * b][NS], NA, acc);
    #pragma unroll
    for (int r = 0; r < 4; ++r) {
      const float4 q4 = *(const float4*)&sC[4 * a + r][4 * b];
      *(float4*)(outJ + (4 * a + r) * NS + 4 * b) =
          make_float4(q4.x - acc[r][0], q4.y - acc[r][1],
                      q4.z - acc[r][2], q4.w - acc[r][3]);
    }
  } else if (tid < 128) {    // A_e = A - BRi·S^T
    const int q = tid - 64, a = q >> 3, b = q & 7;
    float acc[4][4];
    #pragma unroll
    for (int r = 0; r < 4; ++r)
      #pragma unroll
      for (int c = 0; c < 4; ++c) acc[r][c] = 0.f;
    tile_dot<4>(&sBRi[4 * a][0], NI, &sC[4 * b][NS], NA, acc);
    #pragma unroll
    for (int r = 0; r < 4; ++r) {
      const float4 a4 = *(const float4*)&sAB[4 * a + r][4 * b];
      *(float4*)(outA + (4 * a + r) * NS + 4 * b) =
          make_float4(a4.x - acc[r][0], a4.y - acc[r][1],
                      a4.z - acc[r][2], a4.w - acc[r][3]);
    }
  } else if (tid < 192) {    // C_e = BRi·B^T
    const int q = tid - 128, a = q >> 3, b = q & 7;
    float acc[4][4];
    #pragma unroll
    for (int r = 0; r < 4; ++r)
      #pragma unroll
      for (int c = 0; c < 4; ++c) acc[r][c] = 0.f;
    tile_dot<4>(&sBRi[4 * a][0], NI, &sAB[4 * b][NS], NA, acc);
    #pragma unroll
    for (int r = 0; r < 4; ++r)
      *(float4*)(outC + (4 * a + r) * NS + 4 * b) =
          make_float4(acc[r][0], acc[r][1], acc[r][2], acc[r][3]);
  }
}

// ---------------- kernel 2: one suffix-scan level (grid = TT) ----------------
__global__ __launch_bounds__(NTH, 1) void scan_level(
    const float* __restrict__ Sin, float* __restrict__ Sout, int off) {
  const int t = blockIdx.x, tid = threadIdx.x, lane = tid & 63, wid = tid >> 6;
  const float* Ei = Sin + (size_t)t * 3072;
  float* Eo = Sout + (size_t)t * 3072;
  if (t + off >= TT) {               // copy-through
    const float4* src = (const float4*)Ei;
    float4* dst = (float4*)Eo;
    #pragma unroll
    for (int r = 0; r < 3; ++r) dst[tid + 256 * r] = src[tid + 256 * r];
    return;
  }
  const float* Ej = Sin + (size_t)(t + off) * 3072;

  __shared__ float sAi[NS][NS], sCi[NS][NS], sJi[NS][NS];
  __shared__ float sAj[NS][NS], sCj[NS][NS], sJj[NS][NS];
  __shared__ float sAjT[NS][NS];
  __shared__ float sT1[NS][NS], sT1T[NS][NS];
  __shared__ float sY1[NS][NS], sY2[NS][NS], sY3T[NS][NS], sW[NS][NS];
  __shared__ float sX[NS][NS], sZ[NS][NS];

  { // Ph0: loads
    const float4* a4 = (const float4*)Ei;
    ((float4*)sAi)[tid] = a4[tid];
    ((float4*)sCi)[tid] = a4[256 + tid];
    ((float4*)sJi)[tid] = a4[512 + tid];
    const float4* b4 = (const float4*)Ej;
    ((float4*)sAj)[tid] = b4[tid];
    ((float4*)sCj)[tid] = b4[256 + tid];
    ((float4*)sJj)[tid] = b4[512 + tid];
  }
  __syncthreads();
  // AjT build (read in Ph4; barriers in between cover it)
  #pragma unroll
  for (int r = 0; r < 4; ++r) {
    const int e = tid + 256 * r, i = e >> 5, j = e & 31;
    sAjT[j][i] = sAj[i][j];
  }
  // Ph1: X = I + Ci·Jj  (Ci sym -> outer form)
  if (tid < 64) {
    const int a = tid >> 3, b = tid & 7;
    float4 acc[4] = {make_float4(0,0,0,0), make_float4(0,0,0,0),
                     make_float4(0,0,0,0), make_float4(0,0,0,0)};
    tile_outer<NS>(&sCi[0][4 * a], NS, &sJj[0][4 * b], NS, acc);
    if (a == b) { acc[0].x += 1.f; acc[1].y += 1.f; acc[2].z += 1.f; acc[3].w += 1.f; }
    #pragma unroll
    for (int r = 0; r < 4; ++r) *(float4*)&sX[4 * a + r][4 * b] = acc[r];
  }
  __syncthreads();
  // Ph2: wave0 GJ32 -> T1 = X^{-1}  (store T1 and T1^T)
  if (wid == 0) {
    const int c = lane;
    float f[NS];
    #pragma unroll
    for (int i = 0; i < NS; ++i)
      f[i] = (c < NS) ? sX[i][c] : ((c - NS) == i ? 1.f : 0.f);
    #pragma unroll
    for (int k = 0; k < NS; ++k) {
      float mi[NS];
      #pragma unroll
      for (int i = 0; i < NS; ++i) mi[i] = rdlane(f[i], k);
      const float inv = 1.0f / mi[k];
      f[k] *= inv;
      #pragma unroll
      for (int i = 0; i < NS; ++i) if (i != k) f[i] -= mi[i] * f[k];
    }
    if (c >= NS) {
      const int col = c - NS;
      #pragma unroll
      for (int i = 0; i < NS; ++i) sT1[i][col] = f[i];
      #pragma unroll
      for (int q = 0; q < 8; ++q)
        *(float4*)&sT1T[col][4 * q] =
            make_float4(f[4 * q], f[4 * q + 1], f[4 * q + 2], f[4 * q + 3]);
    }
  }
  __syncthreads();
  // Ph3: Y1 = T1·Ai (0..63) | Y2 = T1·Ci (64..127) | Y3T = T1^T·Jj (128..191)
  if (tid < 192) {
    const int grp = tid >> 6, q = tid & 63, a = q >> 3, b = q & 7;
    float4 acc[4] = {make_float4(0,0,0,0), make_float4(0,0,0,0),
                     make_float4(0,0,0,0), make_float4(0,0,0,0)};
    if (grp == 0) {
      tile_outer<NS>(&sT1T[0][4 * a], NS, &sAi[0][4 * b], NS, acc);
      #pragma unroll
      for (int r = 0; r < 4; ++r) *(float4*)&sY1[4 * a + r][4 * b] = acc[r];
    } else if (grp == 1) {
      tile_outer<NS>(&sT1T[0][4 * a], NS, &sCi[0][4 * b], NS, acc);
      #pragma unroll
      for (int r = 0; r < 4; ++r) *(float4*)&sY2[4 * a + r][4 * b] = acc[r];
    } else {
      tile_outer<NS>(&sT1[0][4 * a], NS, &sJj[0][4 * b], NS, acc);
      #pragma unroll
      for (int r = 0; r < 4; ++r) *(float4*)&sY3T[4 * a + r][4 * b] = acc[r];
    }
  }
  __syncthreads();
  // Ph4: A' = Aj·Y1 -> sX | Z = Aj·Y2 -> sZ | W = Y3·Ai -> sW
  if (tid < 192) {
    const int grp = tid >> 6, q = tid & 63, a = q >> 3, b = q & 7;
    float4 acc[4] = {make_float4(0,0,0,0), make_float4(0,0,0,0),
                     make_float4(0,0,0,0), make_float4(0,0,0,0)};
    if (grp == 0) {
      tile_outer<NS>(&sAjT[0][4 * a], NS, &sY1[0][4 * b], NS, acc);
      #pragma unroll
      for (int r = 0; r < 4; ++r) *(float4*)&sX[4 * a + r][4 * b] = acc[r];
    } else if (grp == 1) {
      tile_outer<NS>(&sAjT[0][4 * a], NS, &sY2[0][4 * b], NS, acc);
      #pragma unroll
      for (int r = 0; r < 4; ++r) *(float4*)&sZ[4 * a + r][4 * b] = acc[r];
    } else {
      tile_outer<NS>(&sY3T[0][4 * a], NS, &sAi[0][4 * b], NS, acc);
      #pragma unroll
      for (int r = 0; r < 4; ++r) *(float4*)&sW[4 * a + r][4 * b] = acc[r];
    }
  }
  __syncthreads();
  // Ph5: C' = Z·Aj^T + Cj -> sY2 | J' = Ai^T·W + Ji -> sY1
  if (tid < 64) {
    const int a = tid >> 3, b = tid & 7;
    float acc[4][4];
    #pragma unroll
    for (int r = 0; r < 4; ++r)
      #pragma unroll
      for (int c = 0; c < 4; ++c) acc[r][c] = 0.f;
    tile_dot<8>(&sZ[4 * a][0], NS, &sAj[4 * b][0], NS, acc);
    #pragma unroll
    for (int r = 0; r < 4; ++r) {
      const float4 c4 = *(const float4*)&sCj[4 * a + r][4 * b];
      *(float4*)&sY2[4 * a + r][4 * b] =
          make_float4(acc[r][0] + c4.x, acc[r][1] + c4.y,
                      acc[r][2] + c4.z, acc[r][3] + c4.w);
    }
  } else if (tid < 128) {
    const int q = tid - 64, a = q >> 3, b = q & 7;
    float4 acc[4] = {make_float4(0,0,0,0), make_float4(0,0,0,0),
                     make_float4(0,0,0,0), make_float4(0,0,0,0)};
    tile_outer<NS>(&sAi[0][4 * a], NS, &sW[0][4 * b], NS, acc);
    #pragma unroll
    for (int r = 0; r < 4; ++r) {
      const float4 j4 = *(const float4*)&sJi[4 * a + r][4 * b];
      acc[r].x += j4.x; acc[r].y += j4.y; acc[r].z += j4.z; acc[r].w += j4.w;
      *(float4*)&sY1[4 * a + r][4 * b] = acc[r];
    }
  }
  __syncthreads();
  // Ph6: store A'(sX), C'(sY2), J'(sY1)
  {
    float4* o = (float4*)Eo;
    o[tid]       = ((const float4*)sX)[tid];
    o[256 + tid] = ((const float4*)sY2)[tid];
    o[512 + tid] = ((const float4*)sY1)[tid];
  }
}

// ------------- kernel 3: parallel K_t / M_t extraction (grid = TT) -----------
__global__ __launch_bounds__(NTH, 1) void kmat(
    const float* __restrict__ Sfin, const float* __restrict__ A,
    const float* __restrict__ Bm, const float* __restrict__ C,
    float* __restrict__ Kall, float* __restrict__ Mall) {
  __shared__ float sAB[NS][NA];
  __shared__ float sP [NS][NS];
  __shared__ float sG [NS][NA];
  __shared__ float sFu[NI][NA];
  __shared__ float sK [NI][NS];
  const int t = blockIdx.x, tid = threadIdx.x, lane = tid & 63, wid = tid >> 6;

  for (int e = tid; e < NS * NA; e += NTH) {
    int i = e / NA, j = e % NA;
    sAB[i][j] = (j < NS) ? A[i * NS + j] : Bm[i * NI + (j - NS)];
  }
  if (t == TT - 1) {
    ((float4*)sP)[tid] = make_float4(0.f, 0.f, 0.f, 0.f);
  } else {
    const float4* j4 = (const float4*)(Sfin + (size_t)(t + 1) * 3072 + 2048);
    ((float4*)sP)[tid] = j4[tid];
  }
  // C_t u-row prefetch for Fu tiles
  const int ui = tid / 12, uk = tid - 12 * ui;
  float4 cr0 = make_float4(0,0,0,0), cr1 = make_float4(0,0,0,0);
  float4 cr2 = make_float4(0,0,0,0), cr3 = make_float4(0,0,0,0);
  if (tid < 48) {
    const float* Ct = C + (size_t)t * NA * NA;
    cr0 = *(const float4*)&Ct[(NS + 4 * ui + 0) * NA + 4 * uk];
    cr1 = *(const float4*)&Ct[(NS + 4 * ui + 1) * NA + 4 * uk];
    cr2 = *(const float4*)&Ct[(NS + 4 * ui + 2) * NA + 4 * uk];
    cr3 = *(const float4*)&Ct[(NS + 4 * ui + 3) * NA + 4 * uk];
  }
  __syncthreads();
  // G[i][k] = sum_m P[m][i]·AB[m][k]  (96 tiles, r10-proven form)
  if (tid < 96) {
    const int gi = tid / 12, gk = tid - 12 * gi;
    float4 acc[4] = {make_float4(0,0,0,0), make_float4(0,0,0,0),
                     make_float4(0,0,0,0), make_float4(0,0,0,0)};
    tile_outer<NS>(&sP[0][4 * gi], NS, &sAB[0][4 * gk], NA, acc);
    #pragma unroll
    for (int r = 0; r < 4; ++r) *(float4*)&sG[4 * gi + r][4 * gk] = acc[r];
  }
  __syncthreads();
  // Fu (u-rows of F)
  if (tid < 48) {
    float4 acc[4] = {cr0, cr1, cr2, cr3};
    tile_outer<NS>(&sAB[0][NS + 4 * ui], NA, &sG[0][4 * uk], NA, acc);
    #pragma unroll
    for (int r = 0; r < 4; ++r) *(float4*)&sFu[4 * ui + r][4 * uk] = acc[r];
  }
  __syncthreads();
  // GJ16 (r10-proven; exact divide)
  if (wid == 0) {
    const int col = (lane < 16) ? (NS + lane) : (lane - 16);
    float f[NI];
    #pragma unroll
    for (int i = 0; i < NI; ++i) f[i] = sFu[i][col];
    #pragma unroll
    for (int k = 0; k < NI; ++k) {
      float mi[NI];
      #pragma unroll
      for (int i = 0; i < NI; ++i) mi[i] = rdlane(f[i], k);
      const float inv = 1.0f / mi[k];
      f[k] *= inv;
      #pragma unroll
      for (int i = 0; i < NI; ++i) if (i != k) f[i] -= mi[i] * f[k];
    }
    if (lane >= 16 && lane < 48) {
      const int b = lane - 16;
      #pragma unroll
      for (int i = 0; i < NI; ++i) {
        sK[i][b] = f[i];
        Kall[(size_t)t * NI * NS + i * NS + b] = f[i];
      }
    }
  }
  __syncthreads();
  // M = A - B·K  (64 tiles; r10-proven form)
  if (tid < 64) {
    const int ma = tid >> 3, mb = tid & 7;
    float4 a0 = *(const float4*)&sAB[4 * ma + 0][4 * mb];
    float4 a1 = *(const float4*)&sAB[4 * ma + 1][4 * mb];
    float4 a2 = *(const float4*)&sAB[4 * ma + 2][4 * mb];
    float4 a3 = *(const float4*)&sAB[4 * ma + 3][4 * mb];
    #pragma unroll
    for (int q = 0; q < 4; ++q) {
      const float4 vf0 = *(const float4*)&sAB[4 * ma + 0][NS + 4 * q];
      const float4 vf1 = *(const float4*)&sAB[4 * ma + 1][NS + 4 * q];
      const float4 vf2 = *(const float4*)&sAB[4 * ma + 2][NS + 4 * q];
      const float4 vf3 = *(const float4*)&sAB[4 * ma + 3][NS + 4 * q];
      #pragma unroll
      for (int d = 0; d < 4; ++d) {
        const float4 vkk = *(const float4*)&sK[4 * q + d][4 * mb];
        const float s0 = (d == 0) ? vf0.x : (d == 1) ? vf0.y : (d == 2) ? vf0.z : vf0.w;
        const float s1 = (d == 0) ? vf1.x : (d == 1) ? vf1.y : (d == 2) ? vf1.z : vf1.w;
        const float s2 = (d == 0) ? vf2.x : (d == 1) ? vf2.y : (d == 2) ? vf2.z : vf2.w;
        const float s3 = (d == 0) ? vf3.x : (d == 1) ? vf3.y : (d == 2) ? vf3.z : vf3.w;
        fms4(a0, s0, vkk); fms4(a1, s1, vkk); fms4(a2, s2, vkk); fms4(a3, s3, vkk);
      }
    }
    float4* Mt = (float4*)(Mall + (size_t)t * NS * NS);
    Mt[(4 * ma + 0) * 8 + mb] = a0;
    Mt[(4 * ma + 1) * 8 + mb] = a1;
    Mt[(4 * ma + 2) * 8 + mb] = a2;
    Mt[(4 * ma + 3) * 8 + mb] = a3;
  }
}

// ------------- kernel 4: rollout + u + mu (grid = 1; r10-proven tail) --------
__global__ __launch_bounds__(NTH, 1) void finalize(
    const float* __restrict__ x0, const float* __restrict__ Sfin,
    const float* __restrict__ Kall, const float* __restrict__ Mall,
    float* __restrict__ out) {
  __shared__ float sZx[TT][NS];
  __shared__ float sMb[2 * NS * NS];
  const int tid = threadIdx.x, lane = tid & 63, wid = tid >> 6;

  if (wid == 0) {
    const float4* M4 = (const float4*)Mall;
    float4* sM4 = (float4*)sMb;
    if (lane < NS) { float v = x0[lane]; sZx[0][lane] = v; out[lane] = v; }
    float4 p0 = M4[lane], p1 = M4[64 + lane], p2 = M4[128 + lane], p3 = M4[192 + lane];
    asm volatile("s_waitcnt vmcnt(0)" ::: "memory");
    sM4[lane] = p0; sM4[64 + lane] = p1; sM4[128 + lane] = p2; sM4[192 + lane] = p3;
    asm volatile("s_waitcnt lgkmcnt(0)" ::: "memory");
    __builtin_amdgcn_sched_barrier(0);
    int cur = 0;
    for (int t = 0; t < TT - 1; ++t) {
      const bool pf = (t + 1 < TT - 1);
      if (pf) {
        const int b = (t + 1) * 256;
        p0 = M4[b + lane]; p1 = M4[b + 64 + lane];
        p2 = M4[b + 128 + lane]; p3 = M4[b + 192 + lane];
      }
      if (lane < NS) {
        const float4* xr = (const float4*)&sZx[t][0];
        const float4* mr = sM4 + cur * 256 + 8 * lane;
        float acc = 0.0f;
        #pragma unroll
        for (int q = 0; q < 8; ++q) acc += dot4(mr[q], xr[q]);
        sZx[t + 1][lane] = acc;
        out[(t + 1) * NA + lane] = acc;
      }
      if (pf) {
        asm volatile("s_waitcnt vmcnt(0)" ::: "memory");
        float4* d = sM4 + (cur ^ 1) * 256;
        d[lane] = p0; d[64 + lane] = p1; d[128 + lane] = p2; d[192 + lane] = p3;
      }
      asm volatile("s_waitcnt lgkmcnt(0)" ::: "memory");
      __builtin_amdgcn_sched_barrier(0);
      cur ^= 1;
    }
  }
  __syncthreads();

  // u_t = -K_t x_t
  const float4* K4 = (const float4*)Kall;
  #pragma unroll
  for (int rep = 0; rep < 4; ++rep) {
    const int idx = tid + 256 * rep;
    const int t = idx >> 4, i = idx & 15;
    const float4* xr = (const float4*)&sZx[t][0];
    float acc = 0.0f;
    #pragma unroll
    for (int q = 0; q < 8; ++q) acc += dot4(K4[(size_t)t * 128 + 8 * i + q], xr[q]);
    out[t * NA + NS + i] = -acc;
  }

  // mu_t = (t==0 ? -1 : +1) * P_t x_t,  P_t = J(S_t)
  const float4* S4 = (const float4*)Sfin;
  for (int e = tid; e < TT * NS; e += NTH) {
    const int t = e >> 5, i = e & 31;
    const float4* xr = (const float4*)&sZx[t][0];
    float acc = 0.0f;
    #pragma unroll
    for (int q = 0; q < 8; ++q)
      acc += dot4(S4[(size_t)t * 768 + 512 + 8 * i + q], xr[q]);
    out[NA * TT + e] = (t == 0) ? -acc : acc;
  }
}

} // namespace

extern "C" void kernel_launch(void* const* d_in, const int* in_sizes, int n_in,
                              void* d_out, int out_size, void* d_ws, size_t ws_size,
                              hipStream_t stream) {
  const float* A  = (const float*)d_in[0];
  const float* Bm = (const float*)d_in[1];
  const float* C  = (const float*)d_in[2];
  // d_in[3] is T (==64, compile-time constant here)
  const float* x0 = (const float*)d_in[4];
  float* out = (float*)d_out;

  float* Sb0  = (float*)d_ws;                          // 64*3072 floats
  float* Sb1  = Sb0 + (size_t)TT * 3072;               // 64*3072
  float* Kall = Sb1 + (size_t)TT * 3072;               // 64*512
  float* Mall = Kall + (size_t)TT * NI * NS;           // 64*1024

  hipLaunchKernelGGL(init_elems, dim3(TT), dim3(NTH), 0, stream, A, Bm, C, Sb0);
  float* bufs[2] = {Sb0, Sb1};
  for (int l = 0; l < 6; ++l) {
    hipLaunchKernelGGL(scan_level, dim3(TT), dim3(NTH), 0, stream,
                       bufs[l & 1], bufs[(l + 1) & 1], 1 << l);
  }
  // after 6 levels result is back in Sb0
  hipLaunchKernelGGL(kmat, dim3(TT), dim3(NTH), 0, stream,
                     Sb0, A, Bm, C, Kall, Mall);
  hipLaunchKernelGGL(finalize, dim3(1), dim3(NTH), 0, stream,
                     x0, Sb0, Kall, Mall, out);
}